// Round 1
// baseline (302.564 us; speedup 1.0000x reference)
//
#include <hip/hip_runtime.h>

// Gate-level FP8 E4M3 adder circuit, replayed as integer bit ops.
// Each row = 8 float32 "bits" (sign | exp[4] | man[3], MSB first), value in {0.0,1.0}.
// 1.0f == 0x3F800000 -> bit = (u >> 23) & 1. Output bit b -> b ? 0x3F800000 : 0.

__device__ __forceinline__ unsigned bit_of(unsigned u) { return (u >> 23) & 1u; }
__device__ __forceinline__ unsigned f_of(unsigned b)   { return b ? 0x3F800000u : 0u; }

__global__ __launch_bounds__(256) void fp8_adder_kernel(
    const uint4* __restrict__ A, const uint4* __restrict__ B,
    uint4* __restrict__ O, int n_rows)
{
    int i = blockIdx.x * blockDim.x + threadIdx.x;
    if (i >= n_rows) return;

    uint4 a0 = A[2 * i], a1 = A[2 * i + 1];
    uint4 b0 = B[2 * i], b1 = B[2 * i + 1];

    // Unpack: word order is [sign, e3, e2, e1] [e0, m2, m1, m0] (MSB first)
    unsigned sa = bit_of(a0.x);
    unsigned ea = (bit_of(a0.y) << 3) | (bit_of(a0.z) << 2) | (bit_of(a0.w) << 1) | bit_of(a1.x);
    unsigned ma = (bit_of(a1.y) << 2) | (bit_of(a1.z) << 1) | bit_of(a1.w);
    unsigned sb = bit_of(b0.x);
    unsigned eb = (bit_of(b0.y) << 3) | (bit_of(b0.z) << 2) | (bit_of(b0.w) << 1) | bit_of(b1.x);
    unsigned mb = (bit_of(b1.y) << 2) | (bit_of(b1.z) << 1) | bit_of(b1.w);

    // comparator4 + OR(gt,eq): sel = (ea >= eb)
    unsigned sel = (ea >= eb) ? 1u : 0u;
    unsigned exp_l = sel ? ea : eb, exp_s = sel ? eb : ea;
    unsigned man_l = sel ? ma : mb, man_s = sel ? mb : ma;
    unsigned sign_l = sel ? sa : sb, sign_s = sel ? sb : sa;

    // 4-bit subtract (exp_l >= exp_s, so exact), barrel shift right by diff
    unsigned diff = (exp_l - exp_s) & 0xFu;
    unsigned hid_l = exp_l ? 1u : 0u;
    unsigned hid_s = exp_s ? 1u : 0u;

    // 12-bit extended mantissas, MSB-first bit 11..0: [0, hid, man(3), 0*7]
    unsigned ext_l = (hid_l << 10) | (man_l << 7);
    unsigned ext_s = ((hid_s << 10) | (man_s << 7)) >> diff;

    unsigned same_sign = (sign_l == sign_s);
    // 12-bit ripple add / subtract: both wrap mod 4096 (carry/borrow-out dropped)
    unsigned mant = same_sign ? ((ext_l + ext_s) & 0xFFFu)
                              : ((ext_l - ext_s) & 0xFFFu);

    unsigned top8 = mant >> 4;                 // mant bits 11..4
    // lzd8: leading-zero count of 8-bit value; outputs 7 when top8 == 0
    unsigned lzc = top8 ? (unsigned)(__clz((int)top8) - 24) : 7u;
    unsigned norm = (top8 << lzc) & 0xFFu;     // barrel_left8

    unsigned exp_new = (exp_l - lzc + 1u) & 0xFu;   // subtract_bits + increment4, mod 16
    unsigned man_out = (norm >> 4) & 0x7u;          // norm[1:4] = bits 6..4

    uint4 o0, o1;
    o0.x = f_of(sign_l);
    o0.y = f_of((exp_new >> 3) & 1u);
    o0.z = f_of((exp_new >> 2) & 1u);
    o0.w = f_of((exp_new >> 1) & 1u);
    o1.x = f_of(exp_new & 1u);
    o1.y = f_of((man_out >> 2) & 1u);
    o1.z = f_of((man_out >> 1) & 1u);
    o1.w = f_of(man_out & 1u);

    O[2 * i]     = o0;
    O[2 * i + 1] = o1;
}

extern "C" void kernel_launch(void* const* d_in, const int* in_sizes, int n_in,
                              void* d_out, int out_size, void* d_ws, size_t ws_size,
                              hipStream_t stream) {
    const uint4* A = (const uint4*)d_in[0];
    const uint4* B = (const uint4*)d_in[1];
    uint4* O = (uint4*)d_out;
    int n_rows = in_sizes[0] / 8;
    int block = 256;
    int grid = (n_rows + block - 1) / block;
    fp8_adder_kernel<<<grid, block, 0, stream>>>(A, B, O, n_rows);
}

// Round 3
// 299.995 us; speedup vs baseline: 1.0086x; 1.0086x over previous
//
#include <hip/hip_runtime.h>

// Gate-level FP8 E4M3 adder circuit, replayed as integer bit ops.
// Each row = 8 float32 "bits" (sign | exp4 | man3, MSB first), values in {0.0,1.0}.
// 1.0f == 0x3F800000 -> bit = (u >> 23) & 1. Output bit b -> b ? 0x3F800000 : 0.
//
// R1/R2: 4 rows/thread (16 outstanding dwordx4 loads) + nontemporal loads/stores.
// R0 was MLP-limited at 2.4 TB/s (VALUBusy 8%, only 4 loads in flight/thread).
// R2 fix: __builtin_nontemporal_* needs a native Clang vector type, not HIP uint4.

typedef unsigned int uint32x4 __attribute__((ext_vector_type(4)));

__device__ __forceinline__ unsigned bit_of(unsigned u) { return (u >> 23) & 1u; }
__device__ __forceinline__ unsigned f_of(unsigned b)   { return b ? 0x3F800000u : 0u; }

__device__ __forceinline__ void fp8_add_row(const uint32x4& a0, const uint32x4& a1,
                                            const uint32x4& b0, const uint32x4& b1,
                                            uint32x4& o0, uint32x4& o1)
{
    unsigned sa = bit_of(a0.x);
    unsigned ea = (bit_of(a0.y) << 3) | (bit_of(a0.z) << 2) | (bit_of(a0.w) << 1) | bit_of(a1.x);
    unsigned ma = (bit_of(a1.y) << 2) | (bit_of(a1.z) << 1) | bit_of(a1.w);
    unsigned sb = bit_of(b0.x);
    unsigned eb = (bit_of(b0.y) << 3) | (bit_of(b0.z) << 2) | (bit_of(b0.w) << 1) | bit_of(b1.x);
    unsigned mb = (bit_of(b1.y) << 2) | (bit_of(b1.z) << 1) | bit_of(b1.w);

    // comparator4 + OR(gt,eq): sel = (ea >= eb)
    unsigned sel = (ea >= eb) ? 1u : 0u;
    unsigned exp_l = sel ? ea : eb, exp_s = sel ? eb : ea;
    unsigned man_l = sel ? ma : mb, man_s = sel ? mb : ma;
    unsigned sign_l = sel ? sa : sb, sign_s = sel ? sb : sa;

    unsigned diff = (exp_l - exp_s) & 0xFu;        // 4-bit subtract, exact (l >= s)
    unsigned hid_l = exp_l ? 1u : 0u;
    unsigned hid_s = exp_s ? 1u : 0u;

    // 12-bit extended mantissas, MSB-first bit 11..0: [0, hid, man(3), 0*7]
    unsigned ext_l = (hid_l << 10) | (man_l << 7);
    unsigned ext_s = ((hid_s << 10) | (man_s << 7)) >> diff;

    unsigned same_sign = (sign_l == sign_s);
    // 12-bit ripple add/sub both wrap mod 4096 (carry/borrow-out dropped)
    unsigned mant = same_sign ? ((ext_l + ext_s) & 0xFFFu)
                              : ((ext_l - ext_s) & 0xFFFu);

    unsigned top8 = mant >> 4;                     // mant bits 11..4
    unsigned lzc = top8 ? (unsigned)(__clz((int)top8) - 24) : 7u;  // lzd8 -> 7 on zero
    unsigned norm = (top8 << lzc) & 0xFFu;         // barrel_left8

    unsigned exp_new = (exp_l - lzc + 1u) & 0xFu;  // subtract_bits + increment4, mod 16
    unsigned man_out = (norm >> 4) & 0x7u;         // norm[1:4] = bits 6..4

    o0.x = f_of(sign_l);
    o0.y = f_of((exp_new >> 3) & 1u);
    o0.z = f_of((exp_new >> 2) & 1u);
    o0.w = f_of((exp_new >> 1) & 1u);
    o1.x = f_of(exp_new & 1u);
    o1.y = f_of((man_out >> 2) & 1u);
    o1.z = f_of((man_out >> 1) & 1u);
    o1.w = f_of(man_out & 1u);
}

constexpr int ROWS_PER_THREAD = 4;
constexpr int BLOCK = 256;

__global__ __launch_bounds__(BLOCK) void fp8_adder_kernel(
    const uint32x4* __restrict__ A, const uint32x4* __restrict__ B,
    uint32x4* __restrict__ O, int n_rows)
{
    int base = blockIdx.x * (BLOCK * ROWS_PER_THREAD) + threadIdx.x;

    uint32x4 a0[ROWS_PER_THREAD], a1[ROWS_PER_THREAD];
    uint32x4 b0[ROWS_PER_THREAD], b1[ROWS_PER_THREAD];
    bool valid[ROWS_PER_THREAD];

    // Issue all loads first: 16 dwordx4 in flight per thread.
    #pragma unroll
    for (int k = 0; k < ROWS_PER_THREAD; ++k) {
        int i = base + k * BLOCK;
        valid[k] = (i < n_rows);
        if (valid[k]) {
            a0[k] = __builtin_nontemporal_load(&A[2 * i]);
            a1[k] = __builtin_nontemporal_load(&A[2 * i + 1]);
            b0[k] = __builtin_nontemporal_load(&B[2 * i]);
            b1[k] = __builtin_nontemporal_load(&B[2 * i + 1]);
        }
    }

    #pragma unroll
    for (int k = 0; k < ROWS_PER_THREAD; ++k) {
        if (valid[k]) {
            int i = base + k * BLOCK;
            uint32x4 o0, o1;
            fp8_add_row(a0[k], a1[k], b0[k], b1[k], o0, o1);
            __builtin_nontemporal_store(o0, &O[2 * i]);
            __builtin_nontemporal_store(o1, &O[2 * i + 1]);
        }
    }
}

extern "C" void kernel_launch(void* const* d_in, const int* in_sizes, int n_in,
                              void* d_out, int out_size, void* d_ws, size_t ws_size,
                              hipStream_t stream) {
    const uint32x4* A = (const uint32x4*)d_in[0];
    const uint32x4* B = (const uint32x4*)d_in[1];
    uint32x4* O = (uint32x4*)d_out;
    int n_rows = in_sizes[0] / 8;
    int rows_per_block = BLOCK * ROWS_PER_THREAD;
    int grid = (n_rows + rows_per_block - 1) / rows_per_block;
    fp8_adder_kernel<<<grid, BLOCK, 0, stream>>>(A, B, O, n_rows);
}